// Round 6
// baseline (269.425 us; speedup 1.0000x reference)
//
#include <hip/hip_runtime.h>
#include <math.h>

#define REGION_MAX 116
#define EMB 768
#define EMB4 192          // EMB / 4 float4s per row
#define DIM_D 182
#define DIM_H 218
#define DIM_W 182
#define PPB 32            // points (output rows) per block
#define BLOCK 256
#define PASSES 3          // DIAGNOSTIC: repeat phase B (idempotent writes) so
                          // the copy phase exceeds the ~120us poison fills and
                          // finally surfaces in the rocprof top-5 with counters.
                          // Pass time = (dur_R6 - dur_R5) / (PASSES-1).

typedef float v4f __attribute__((ext_vector_type(4)));

__global__ __launch_bounds__(BLOCK) void fused_embed_kernel(
    const float* __restrict__ centers,   // [P,3]
    const float* __restrict__ mri,       // [4,4]
    const float* __restrict__ aal,       // [4,4]
    const float* __restrict__ vol,       // [D,H,W]
    const float* __restrict__ table,     // [117, EMB]
    float* __restrict__ out,             // [P, EMB]
    int P) {
    __shared__ float M[12];
    __shared__ int rids[PPB];

    if (threadIdx.x == 0) {
        // M = inv(aal) @ mri, top 3 rows. Gauss-Jordan w/ partial pivoting
        // (matches jnp.linalg.inv numerics; absmax==0 across all rounds).
        float a[4][8];
        for (int i = 0; i < 4; ++i)
            for (int j = 0; j < 4; ++j) {
                a[i][j]     = aal[i * 4 + j];
                a[i][j + 4] = (i == j) ? 1.0f : 0.0f;
            }
        for (int c = 0; c < 4; ++c) {
            int piv = c;
            float best = fabsf(a[c][c]);
            for (int r = c + 1; r < 4; ++r) {
                float v = fabsf(a[r][c]);
                if (v > best) { best = v; piv = r; }
            }
            if (piv != c)
                for (int j = 0; j < 8; ++j) {
                    float t = a[c][j]; a[c][j] = a[piv][j]; a[piv][j] = t;
                }
            float inv = 1.0f / a[c][c];
            for (int j = 0; j < 8; ++j) a[c][j] *= inv;
            for (int r = 0; r < 4; ++r) {
                if (r == c) continue;
                float f = a[r][c];
                for (int j = 0; j < 8; ++j) a[r][j] -= f * a[c][j];
            }
        }
        for (int i = 0; i < 3; ++i)
            for (int j = 0; j < 4; ++j) {
                float s = 0.0f;
                for (int k = 0; k < 4; ++k) s += a[i][4 + k] * mri[k * 4 + j];
                M[i * 4 + j] = s;
            }
    }
    __syncthreads();

    const int base = blockIdx.x * PPB;

    // phase A: 32 threads compute region ids into LDS (runs ONCE)
    if (threadIdx.x < PPB) {
        const int p = base + threadIdx.x;
        int r = 0;
        if (p < P) {
            float px = centers[p * 3 + 0];
            float py = centers[p * 3 + 1];
            float pz = centers[p * 3 + 2];

            float fx = M[0] * px + M[1] * py + M[2]  * pz + M[3];
            float fy = M[4] * px + M[5] * py + M[6]  * pz + M[7];
            float fz = M[8] * px + M[9] * py + M[10] * pz + M[11];

            int x = (int)rintf(fx);   // round half-to-even, matches jnp.round
            int y = (int)rintf(fy);
            int z = (int)rintf(fz);

            bool inb = (x >= 0) & (x < DIM_D) & (y >= 0) & (y < DIM_H) &
                       (z >= 0) & (z < DIM_W);
            int cx = min(max(x, 0), DIM_D - 1);
            int cy = min(max(y, 0), DIM_H - 1);
            int cz = min(max(z, 0), DIM_W - 1);

            int region = (int)vol[((size_t)cx * DIM_H + cy) * DIM_W + cz];
            r = (inb && region >= 0 && region <= REGION_MAX) ? region : 0;
        }
        rids[threadIdx.x] = r;
    }
    __syncthreads();

    // phase B: stream PPB rows (contiguous 96 KB). Repeated PASSES times with
    // identical addresses+values (idempotent -> output unchanged). The memory
    // clobber + barrier between passes prevents dead-store elimination of
    // earlier passes and load-CSE into later passes: each pass re-issues the
    // full 192MiB-equivalent load+store traffic.
    const int npts = min(PPB, P - base);
    const v4f* __restrict__ tab4 = (const v4f*)table;
    v4f* __restrict__ out4 = (v4f*)out + (long)base * EMB4;

    for (int pass = 0; pass < PASSES; ++pass) {
        if (npts == PPB) {
            #pragma unroll 4
            for (unsigned j = threadIdx.x; j < (unsigned)(PPB * EMB4); j += BLOCK) {
                unsigned p = j / (unsigned)EMB4;      // 32-bit magic-mul
                unsigned c = j - p * (unsigned)EMB4;
                out4[j] = tab4[(unsigned)rids[p] * (unsigned)EMB4 + c];
            }
        } else {
            for (unsigned j = threadIdx.x; j < (unsigned)(npts * EMB4); j += BLOCK) {
                unsigned p = j / (unsigned)EMB4;
                unsigned c = j - p * (unsigned)EMB4;
                out4[j] = tab4[(unsigned)rids[p] * (unsigned)EMB4 + c];
            }
        }
        __syncthreads();
        asm volatile("" ::: "memory");   // block DSE/CSE across passes
    }
}

extern "C" void kernel_launch(void* const* d_in, const int* in_sizes, int n_in,
                              void* d_out, int out_size, void* d_ws, size_t ws_size,
                              hipStream_t stream) {
    const float* centers = (const float*)d_in[0];   // [B,N,3] f32
    const float* mri     = (const float*)d_in[1];   // [4,4]
    const float* aal     = (const float*)d_in[2];   // [4,4]
    const float* vol     = (const float*)d_in[3];   // [D,H,W]
    const float* table   = (const float*)d_in[4];   // [117,768]
    float* out = (float*)d_out;

    int P = in_sizes[0] / 3;                        // 65536
    int blocks = (P + PPB - 1) / PPB;               // 2048
    fused_embed_kernel<<<blocks, BLOCK, 0, stream>>>(
        centers, mri, aal, vol, table, out, P);
}

// Round 7
// 221.137 us; speedup vs baseline: 1.2184x; 1.2184x over previous
//
#include <hip/hip_runtime.h>
#include <math.h>

#define REGION_MAX 116
#define EMB 768
#define EMB4 192          // EMB / 4 float4s per row
#define DIM_D 182
#define DIM_H 218
#define DIM_W 182
#define PPB 32            // points (output rows) per block
#define BLOCK 256

typedef float v4f __attribute__((ext_vector_type(4)));

// FINAL (R7 = R4 revert): fused region-id + embedding copy.
// R6's 3-pass diagnostic measured ONE copy pass at ~23 us (269.4-222.8)/2:
// the 192 MiB output fits the 256 MiB Infinity Cache, so stores complete at
// ~8.6 TB/s apparent into L3 — at/below the write roofline. The remaining
// ~197 us of dur_us is harness-owned poison/restore fills (805 MB ws fill at
// ~120 us etc.), untouchable from kernel_launch. Kernel-side: ~roofline.
__global__ __launch_bounds__(BLOCK) void fused_embed_kernel(
    const float* __restrict__ centers,   // [P,3]
    const float* __restrict__ mri,       // [4,4]
    const float* __restrict__ aal,       // [4,4]
    const float* __restrict__ vol,       // [D,H,W]
    const float* __restrict__ table,     // [117, EMB]
    float* __restrict__ out,             // [P, EMB]
    int P) {
    __shared__ float M[12];
    __shared__ int rids[PPB];

    if (threadIdx.x == 0) {
        // M = inv(aal) @ mri, top 3 rows. Gauss-Jordan w/ partial pivoting
        // (matches jnp.linalg.inv numerics; absmax==0 across all rounds).
        float a[4][8];
        for (int i = 0; i < 4; ++i)
            for (int j = 0; j < 4; ++j) {
                a[i][j]     = aal[i * 4 + j];
                a[i][j + 4] = (i == j) ? 1.0f : 0.0f;
            }
        for (int c = 0; c < 4; ++c) {
            int piv = c;
            float best = fabsf(a[c][c]);
            for (int r = c + 1; r < 4; ++r) {
                float v = fabsf(a[r][c]);
                if (v > best) { best = v; piv = r; }
            }
            if (piv != c)
                for (int j = 0; j < 8; ++j) {
                    float t = a[c][j]; a[c][j] = a[piv][j]; a[piv][j] = t;
                }
            float inv = 1.0f / a[c][c];
            for (int j = 0; j < 8; ++j) a[c][j] *= inv;
            for (int r = 0; r < 4; ++r) {
                if (r == c) continue;
                float f = a[r][c];
                for (int j = 0; j < 8; ++j) a[r][j] -= f * a[c][j];
            }
        }
        for (int i = 0; i < 3; ++i)
            for (int j = 0; j < 4; ++j) {
                float s = 0.0f;
                for (int k = 0; k < 4; ++k) s += a[i][4 + k] * mri[k * 4 + j];
                M[i * 4 + j] = s;
            }
    }
    __syncthreads();

    const int base = blockIdx.x * PPB;

    // phase A: 32 threads compute region ids into LDS
    if (threadIdx.x < PPB) {
        const int p = base + threadIdx.x;
        int r = 0;
        if (p < P) {
            float px = centers[p * 3 + 0];
            float py = centers[p * 3 + 1];
            float pz = centers[p * 3 + 2];

            float fx = M[0] * px + M[1] * py + M[2]  * pz + M[3];
            float fy = M[4] * px + M[5] * py + M[6]  * pz + M[7];
            float fz = M[8] * px + M[9] * py + M[10] * pz + M[11];

            int x = (int)rintf(fx);   // round half-to-even, matches jnp.round
            int y = (int)rintf(fy);
            int z = (int)rintf(fz);

            bool inb = (x >= 0) & (x < DIM_D) & (y >= 0) & (y < DIM_H) &
                       (z >= 0) & (z < DIM_W);
            int cx = min(max(x, 0), DIM_D - 1);
            int cy = min(max(y, 0), DIM_H - 1);
            int cz = min(max(z, 0), DIM_W - 1);

            int region = (int)vol[((size_t)cx * DIM_H + cy) * DIM_W + cz];
            r = (inb && region >= 0 && region <= REGION_MAX) ? region : 0;
        }
        rids[threadIdx.x] = r;
    }
    __syncthreads();

    // phase B: stream PPB rows (contiguous 96 KB) of embeddings.
    // table (359 KB) L2-resident; output stores land in L3 (~23 us/pass).
    const int npts = min(PPB, P - base);
    const v4f* __restrict__ tab4 = (const v4f*)table;
    v4f* __restrict__ out4 = (v4f*)out + (long)base * EMB4;

    if (npts == PPB) {
        #pragma unroll 4
        for (unsigned j = threadIdx.x; j < (unsigned)(PPB * EMB4); j += BLOCK) {
            unsigned p = j / (unsigned)EMB4;      // 32-bit magic-mul
            unsigned c = j - p * (unsigned)EMB4;
            out4[j] = tab4[(unsigned)rids[p] * (unsigned)EMB4 + c];
        }
    } else {
        for (unsigned j = threadIdx.x; j < (unsigned)(npts * EMB4); j += BLOCK) {
            unsigned p = j / (unsigned)EMB4;
            unsigned c = j - p * (unsigned)EMB4;
            out4[j] = tab4[(unsigned)rids[p] * (unsigned)EMB4 + c];
        }
    }
}

extern "C" void kernel_launch(void* const* d_in, const int* in_sizes, int n_in,
                              void* d_out, int out_size, void* d_ws, size_t ws_size,
                              hipStream_t stream) {
    const float* centers = (const float*)d_in[0];   // [B,N,3] f32
    const float* mri     = (const float*)d_in[1];   // [4,4]
    const float* aal     = (const float*)d_in[2];   // [4,4]
    const float* vol     = (const float*)d_in[3];   // [D,H,W]
    const float* table   = (const float*)d_in[4];   // [117,768]
    float* out = (float*)d_out;

    int P = in_sizes[0] / 3;                        // 65536
    int blocks = (P + PPB - 1) / PPB;               // 2048
    fused_embed_kernel<<<blocks, BLOCK, 0, stream>>>(
        centers, mri, aal, vol, table, out, P);
}